// Round 9
// baseline (455.777 us; speedup 1.0000x reference)
//
#include <hip/hip_runtime.h>
#include <hip/hip_bf16.h>
#include <cstdint>

// MoE feed-forward, routed top-2 of 8 experts.
// B=2 S=2048 D=1024 F=2048 E=8 K=2.
// R14: parallel routing. R13 accounting: kernels sum ~280 us but total 440 ->
//   ~160 us unaccounted. Suspect: route_kernel = ONE block / 16 waves doing
//   16K scattered global stores = single-CU latency-bound serial stage
//   (bounded only by the 109 us top-5 cutoff). Within-expert order is FREE
//   (atomic combine; hidden rows permuted consistently producer->consumer),
//   so: route_count (32 blk, wave-aggregated atomics: 8 ballots + 1 atomic
//   per expert per wave ~ 1024 total, not R4's 8192-on-one-line) ->
//   route_scan (tiny) -> route_scatter (32 blk, same aggregation on ctr2).
//   wcvt grid 2048->8192. GEMMs byte-identical to R13 (rgemm12 109 us
//   verified, MfmaUtil 27.8%; NO setprio per R12's -30% lesson).

#define Dd 1024
#define Ff 2048
#define Ee 8
#define TOK 4096
#define PAIRS 8192

typedef __attribute__((ext_vector_type(8))) short short8;
typedef __attribute__((ext_vector_type(4))) float floatx4;

__device__ __forceinline__ unsigned short f2bf(float f) {
    unsigned int u = __float_as_uint(f);
    unsigned int r = (u + 0x7FFFu + ((u >> 16) & 1u)) >> 16;
    return (unsigned short)r;
}
__device__ __forceinline__ float bf2f(unsigned short u) {
    return __uint_as_float(((unsigned)u) << 16);
}

// async 16B/lane global->LDS. lds ptr is wave-uniform; lane i lands at lds + i*16B.
__device__ __forceinline__ void gload16(const unsigned short* g, unsigned short* l) {
    __builtin_amdgcn_global_load_lds(
        (const __attribute__((address_space(1))) unsigned int*)g,
        (__attribute__((address_space(3))) unsigned int*)l,
        16, 0, 0);
}

// ---------------- zero out ----------------
__global__ void zero_kernel(float* __restrict__ out, int n4) {
    int i = blockIdx.x * blockDim.x + threadIdx.x;
    if (i < n4) reinterpret_cast<float4*>(out)[i] = make_float4(0.f, 0.f, 0.f, 0.f);
}

// ---------------- gating + x->bf16: fp32 scores, top-2, softmax (NO atomics) ----------------
__global__ void gating_kernel(const float* __restrict__ x, const float* __restrict__ Wg,
                              int* __restrict__ tok_idx, float* __restrict__ tok_prob,
                              unsigned short* __restrict__ xb) {
    int lane = threadIdx.x & 63;
    int w = threadIdx.x >> 6;
    int t = blockIdx.x * 4 + w;

    float xr[16];
    const float* xp = x + (size_t)t * Dd;
#pragma unroll
    for (int i = 0; i < 16; i++) xr[i] = xp[lane + i * 64];

    // fused x -> bf16 (row is already in registers)
    unsigned short* xbp = xb + (size_t)t * Dd;
#pragma unroll
    for (int i = 0; i < 16; i++) xbp[lane + i * 64] = f2bf(xr[i]);

    float sc[Ee];
    for (int e = 0; e < Ee; e++) {
        const float* wp = Wg + (size_t)e * Dd;
        float p = 0.f;
#pragma unroll
        for (int i = 0; i < 16; i++) p += xr[i] * wp[lane + i * 64];
        for (int off = 32; off > 0; off >>= 1) p += __shfl_xor(p, off);
        sc[e] = p;
    }
    if (lane == 0) {
        int e1 = 0, e2 = 0;
        float b1 = -1e30f, b2 = -1e30f;
        for (int e = 0; e < Ee; e++) {
            float s = sc[e];
            if (s > b1) { b2 = b1; e2 = e1; b1 = s; e1 = e; }
            else if (s > b2) { b2 = s; e2 = e; }
        }
        float p1 = 1.f / (1.f + expf(b2 - b1));
        float p2 = 1.f - p1;
        tok_idx[t * 2 + 0] = e1;
        tok_idx[t * 2 + 1] = e2;
        tok_prob[t * 2 + 0] = p1;
        tok_prob[t * 2 + 1] = p2;
    }
}

// ---------------- route stage 1: wave-aggregated expert counts ----------------
// 32 blocks x 256 thr, 1 item/thread. Per wave: 8 ballots, <=1 atomic per
// present expert (leader lane) -> ~1024 atomics total over 8 counters.
__global__ void route_count(const int* __restrict__ tok_idx, int* __restrict__ ctr) {
    int item = blockIdx.x * 256 + threadIdx.x;
    int lane = threadIdx.x & 63;
    int e = tok_idx[item];
#pragma unroll
    for (int k = 0; k < Ee; k++) {
        unsigned long long m = __ballot(e == k);
        if (m != 0ull && lane == __ffsll(m) - 1)
            atomicAdd(&ctr[k], (int)__popcll(m));
    }
}

// ---------------- route stage 2: tiny scan -> meta, zero ctr2 ----------------
__global__ void route_scan(const int* __restrict__ ctr, int* __restrict__ meta,
                           int* __restrict__ ctr2) {
    if (threadIdx.x == 0) {
        int b = 0;
        for (int e = 0; e < Ee; e++) {
            int c = ctr[e];
            meta[e] = c;          // counts
            meta[16 + e] = b;     // bases
            ctr2[e] = 0;
            b += c;
        }
    }
}

// ---------------- route stage 3: wave-aggregated scatter ----------------
// Same aggregation against ctr2 for within-expert positions. Order within an
// expert is nondeterministic but consistent (list_tok/list_prob written
// together; hidden rows permuted identically for producer and consumer).
__global__ void route_scatter(const int* __restrict__ tok_idx,
                              const float* __restrict__ tok_prob,
                              const int* __restrict__ meta, int* __restrict__ ctr2,
                              int* __restrict__ list_tok, float* __restrict__ list_prob) {
    int item = blockIdx.x * 256 + threadIdx.x;
    int lane = threadIdx.x & 63;
    int e = tok_idx[item];
    unsigned long long lower = (1ull << lane) - 1ull;
#pragma unroll
    for (int k = 0; k < Ee; k++) {
        unsigned long long m = __ballot(e == k);
        if (m != 0ull) {
            int leader = __ffsll(m) - 1;
            int base = 0;
            if (lane == leader) base = atomicAdd(&ctr2[k], (int)__popcll(m));
            base = __shfl(base, leader);
            if (e == k) {
                int pos = meta[16 + k] + base + (int)__popcll(m & lower);
                list_tok[pos] = item >> 1;
                list_prob[pos] = tok_prob[item];
            }
        }
    }
}

// ---------------- all-weights fp32 -> bf16, one grid-stride launch ----------------
__global__ void wcvt_kernel(const float* __restrict__ W1, const float* __restrict__ W2,
                            const float* __restrict__ W3,
                            unsigned short* __restrict__ W1b, unsigned short* __restrict__ W2b,
                            unsigned short* __restrict__ W3b) {
    const int n4 = Ee * Ff * Dd / 4;          // 4M = 2^22
    int stride = gridDim.x * blockDim.x;
    for (int i = blockIdx.x * blockDim.x + threadIdx.x; i < 3 * n4; i += stride) {
        int t = i >> 22;
        int j = i & (n4 - 1);
        const float* src = (t == 0) ? W1 : (t == 1) ? W2 : W3;
        unsigned short* dst = (t == 0) ? W1b : (t == 1) ? W2b : W3b;
        float4 v = reinterpret_cast<const float4*>(src)[j];
        uint2 o;
        o.x = (unsigned)f2bf(v.x) | ((unsigned)f2bf(v.y) << 16);
        o.y = (unsigned)f2bf(v.z) | ((unsigned)f2bf(v.w) << 16);
        reinterpret_cast<uint2*>(dst)[j] = o;
    }
}

// ---------------- manual fp32->bf16 LDS staging (fallback path only, linear) ----------------
__device__ __forceinline__ void stage16(unsigned short* dst, const float* src) {
    const float4* s = reinterpret_cast<const float4*>(src);
    float4 v0 = s[0], v1 = s[1], v2 = s[2], v3 = s[3];
    uint4 o0, o1;
    o0.x = (unsigned)f2bf(v0.x) | ((unsigned)f2bf(v0.y) << 16);
    o0.y = (unsigned)f2bf(v0.z) | ((unsigned)f2bf(v0.w) << 16);
    o0.z = (unsigned)f2bf(v1.x) | ((unsigned)f2bf(v1.y) << 16);
    o0.w = (unsigned)f2bf(v1.z) | ((unsigned)f2bf(v1.w) << 16);
    o1.x = (unsigned)f2bf(v2.x) | ((unsigned)f2bf(v2.y) << 16);
    o1.y = (unsigned)f2bf(v2.z) | ((unsigned)f2bf(v2.w) << 16);
    o1.z = (unsigned)f2bf(v3.x) | ((unsigned)f2bf(v3.y) << 16);
    o1.w = (unsigned)f2bf(v3.z) | ((unsigned)f2bf(v3.w) << 16);
    uint4* d = reinterpret_cast<uint4*>(dst);
    d[0] = o0;
    d[1] = o1;
}

// ============ fused gemm1 (persistent): hidden = silu(x W1^T) * (x W2^T) ============
// 128x128 tile, BK=32, 4 waves (2Mx2N, 64x64/wave), dual acc, counted-vmcnt
// 2-deep (vmcnt(6)), XOR chunk swizzle both sides. NO setprio (R12: -30%).
// Persistent: 768 blocks grid-stride over active tiles (e-major, mblk, nblk fastest).
__global__ __launch_bounds__(256, 2) void rgemm12_kernel(
    const unsigned short* __restrict__ A,      // xb
    const unsigned short* __restrict__ B1w,    // W1b
    const unsigned short* __restrict__ B2w,    // W2b
    unsigned short* __restrict__ hout,         // hidden (bf16)
    const int* __restrict__ list_tok, const int* __restrict__ meta) {
    __shared__ unsigned short sA[2 * 128 * 32];
    __shared__ unsigned short sB1[2 * 128 * 32];
    __shared__ unsigned short sB2[2 * 128 * 32];

    int tid = threadIdx.x;
    int lane = tid & 63, w = tid >> 6;
    int wm = w >> 1, wn = w & 1;
    int lane15 = lane & 15, quad = lane >> 4;

    int jr = w * 32 + (lane >> 2);
    int c8 = (((lane & 3) ^ ((lane >> 3) & 3)) * 8);
    unsigned short* ldsA0  = sA  + w * 1024;
    unsigned short* ldsA1  = ldsA0 + 512;
    unsigned short* ldsB10 = sB1 + w * 1024;
    unsigned short* ldsB11 = ldsB10 + 512;
    unsigned short* ldsB20 = sB2 + w * 1024;
    unsigned short* ldsB21 = ldsB20 + 512;

    int rsw = (lane15 >> 1) & 3;
    const unsigned short* sAr  = &sA [(wm * 64 + lane15) * 32 + (quad ^ rsw) * 8];
    const unsigned short* sB1r = &sB1[(wn * 64 + lane15) * 32 + (quad ^ rsw) * 8];
    const unsigned short* sB2r = &sB2[(wn * 64 + lane15) * 32 + (quad ^ rsw) * 8];

    int cntv[Ee], basv[Ee], itemsv[Ee];
    int total = 0;
#pragma unroll
    for (int ee = 0; ee < Ee; ee++) {
        cntv[ee] = meta[ee];
        basv[ee] = meta[16 + ee];
        itemsv[ee] = ((cntv[ee] + 127) >> 7) * 16;   // mblks * 16 nblks
        total += itemsv[ee];
    }

    for (int item = blockIdx.x; item < total; item += gridDim.x) {
        int rem = item, e = 0, done = 0;
#pragma unroll
        for (int ee = 0; ee < Ee - 1; ee++) {
            if (!done) {
                if (rem >= itemsv[ee]) { rem -= itemsv[ee]; e = ee + 1; }
                else done = 1;
            }
        }
        int mblk = rem >> 4, nblk = rem & 15;
        int cnt = cntv[e], bs = basv[e];
        int m0 = mblk * 128, n0 = nblk * 128;

        int r0 = m0 + jr;      if (r0 >= cnt) r0 = cnt - 1;
        int r1 = m0 + jr + 16; if (r1 >= cnt) r1 = cnt - 1;
        size_t ar0 = (size_t)list_tok[bs + r0];
        size_t ar1 = (size_t)list_tok[bs + r1];
        const unsigned short* a0 = A + ar0 * Dd + c8;
        const unsigned short* a1 = A + ar1 * Dd + c8;
        const unsigned short* b10 = B1w + ((size_t)e * Ff + n0 + jr) * Dd + c8;
        const unsigned short* b11 = b10 + (size_t)16 * Dd;
        const unsigned short* b20 = B2w + ((size_t)e * Ff + n0 + jr) * Dd + c8;
        const unsigned short* b21 = b20 + (size_t)16 * Dd;

        floatx4 acc1[4][4] = {};
        floatx4 acc2[4][4] = {};

#pragma unroll
        for (int t = 0; t < 2; t++) {
            int k = t * 32, o = t * 4096;
            gload16(a0 + k,  ldsA0  + o);
            gload16(a1 + k,  ldsA1  + o);
            gload16(b10 + k, ldsB10 + o);
            gload16(b11 + k, ldsB11 + o);
            gload16(b20 + k, ldsB20 + o);
            gload16(b21 + k, ldsB21 + o);
        }

        int cur = 0;
        for (int t = 0; t < 32; ++t) {
            if (t < 31) asm volatile("s_waitcnt vmcnt(6)" ::: "memory");
            else        asm volatile("s_waitcnt vmcnt(0)" ::: "memory");
            __builtin_amdgcn_s_barrier();
            asm volatile("" ::: "memory");

            int o = cur * 4096;
            short8 af[4], b1f[4], b2f[4];
#pragma unroll
            for (int i = 0; i < 4; i++) {
                af[i]  = *reinterpret_cast<const short8*>(sAr  + o + i * 16 * 32);
                b1f[i] = *reinterpret_cast<const short8*>(sB1r + o + i * 16 * 32);
                b2f[i] = *reinterpret_cast<const short8*>(sB2r + o + i * 16 * 32);
            }
#pragma unroll
            for (int mi = 0; mi < 4; mi++)
#pragma unroll
                for (int ni = 0; ni < 4; ni++) {
                    acc1[mi][ni] = __builtin_amdgcn_mfma_f32_16x16x32_bf16(af[mi], b1f[ni], acc1[mi][ni], 0, 0, 0);
                    acc2[mi][ni] = __builtin_amdgcn_mfma_f32_16x16x32_bf16(af[mi], b2f[ni], acc2[mi][ni], 0, 0, 0);
                }
            asm volatile("" ::: "memory");
            __builtin_amdgcn_s_barrier();   // all waves done reading buf[cur]
            asm volatile("" ::: "memory");
            if (t + 2 < 32) {
                int k = (t + 2) * 32;
                gload16(a0 + k,  ldsA0  + o);
                gload16(a1 + k,  ldsA1  + o);
                gload16(b10 + k, ldsB10 + o);
                gload16(b11 + k, ldsB11 + o);
                gload16(b20 + k, ldsB20 + o);
                gload16(b21 + k, ldsB21 + o);
            }
            cur ^= 1;
        }

        // epilogue: hidden = silu(h1) * h2 on fp32 acc
#pragma unroll
        for (int mi = 0; mi < 4; mi++) {
#pragma unroll
            for (int i = 0; i < 4; i++) {
                int rr = m0 + wm * 64 + mi * 16 + quad * 4 + i;
                if (rr < cnt) {
                    int pos = bs + rr;
                    unsigned short* hp = hout + (size_t)pos * Ff + n0 + wn * 64;
#pragma unroll
                    for (int ni = 0; ni < 4; ni++) {
                        float h1 = acc1[mi][ni][i];
                        float h2 = acc2[mi][ni][i];
                        float hv = h1 / (1.f + expf(-h1)) * h2;
                        hp[ni * 16 + lane15] = f2bf(hv);
                    }
                }
            }
        }
    }
}

// ============ gemm2 + combine (persistent, split-K2): out[tok] += p * (hidden W3^T) ============
// 128x128 tile, K=2048 split into 2 halves of 1024 -> 1024 items (4 blocks/CU).
// Partials feed the atomic combine (4 contributions/elem). NO setprio.
__global__ __launch_bounds__(256, 2) void rg2_kernel(
    const unsigned short* __restrict__ A,      // hidden
    const unsigned short* __restrict__ B3,     // W3b (e, d, f)
    float* __restrict__ out,                   // token-indexed atomic output
    const int* __restrict__ list_tok, const float* __restrict__ list_prob,
    const int* __restrict__ meta) {
    __shared__ unsigned short sA[2 * 128 * 32];
    __shared__ unsigned short sB[2 * 128 * 32];

    int tid = threadIdx.x;
    int lane = tid & 63, w = tid >> 6;
    int wm = w >> 1, wn = w & 1;
    int lane15 = lane & 15, quad = lane >> 4;

    int jr = w * 32 + (lane >> 2);
    int c8 = (((lane & 3) ^ ((lane >> 3) & 3)) * 8);
    unsigned short* ldsA0 = sA + w * 1024;
    unsigned short* ldsA1 = ldsA0 + 512;
    unsigned short* ldsB0 = sB + w * 1024;
    unsigned short* ldsB1 = ldsB0 + 512;

    int rsw = (lane15 >> 1) & 3;
    const unsigned short* sAr = &sA[(wm * 64 + lane15) * 32 + (quad ^ rsw) * 8];
    const unsigned short* sBr = &sB[(wn * 64 + lane15) * 32 + (quad ^ rsw) * 8];

    int cntv[Ee], basv[Ee], itemsv[Ee];
    int total = 0;
#pragma unroll
    for (int ee = 0; ee < Ee; ee++) {
        cntv[ee] = meta[ee];
        basv[ee] = meta[16 + ee];
        itemsv[ee] = ((cntv[ee] + 127) >> 7) * 8 * 2;   // mblks * 8 nblks * 2 khalf
        total += itemsv[ee];
    }

    for (int item = blockIdx.x; item < total; item += gridDim.x) {
        int rem = item, e = 0, done = 0;
#pragma unroll
        for (int ee = 0; ee < Ee - 1; ee++) {
            if (!done) {
                if (rem >= itemsv[ee]) { rem -= itemsv[ee]; e = ee + 1; }
                else done = 1;
            }
        }
        int mb8 = itemsv[e] >> 1;          // mblks * 8
        int kh = (rem >= mb8) ? 1 : 0;
        int rem2 = rem - kh * mb8;
        int mblk = rem2 >> 3, nblk = rem2 & 7;
        int cnt = cntv[e], bs = basv[e];
        int m0 = mblk * 128, n0 = nblk * 128;
        int k0 = kh * 1024;                // K-half offset (elements)

        int r0 = m0 + jr;      if (r0 >= cnt) r0 = cnt - 1;
        int r1 = m0 + jr + 16; if (r1 >= cnt) r1 = cnt - 1;
        const unsigned short* a0 = A + (size_t)(bs + r0) * Ff + k0 + c8;
        const unsigned short* a1 = A + (size_t)(bs + r1) * Ff + k0 + c8;
        const unsigned short* b0 = B3 + ((size_t)e * Dd + n0 + jr) * Ff + k0 + c8;
        const unsigned short* b1 = b0 + (size_t)16 * Ff;

        floatx4 acc[4][4] = {};

#pragma unroll
        for (int t = 0; t < 2; t++) {
            int k = t * 32, o = t * 4096;
            gload16(a0 + k, ldsA0 + o);
            gload16(a1 + k, ldsA1 + o);
            gload16(b0 + k, ldsB0 + o);
            gload16(b1 + k, ldsB1 + o);
        }
        int cur = 0;
        const int NT = 32;   // 1024 / 32
        for (int t = 0; t < NT; ++t) {
            if (t + 1 < NT) asm volatile("s_waitcnt vmcnt(4)" ::: "memory");
            else            asm volatile("s_waitcnt vmcnt(0)" ::: "memory");
            __builtin_amdgcn_s_barrier();
            asm volatile("" ::: "memory");

            int o = cur * 4096;
            short8 af[4], bfr[4];
#pragma unroll
            for (int i = 0; i < 4; i++) {
                af[i]  = *reinterpret_cast<const short8*>(sAr + o + i * 16 * 32);
                bfr[i] = *reinterpret_cast<const short8*>(sBr + o + i * 16 * 32);
            }
#pragma unroll
            for (int mi = 0; mi < 4; mi++)
#pragma unroll
                for (int ni = 0; ni < 4; ni++)
                    acc[mi][ni] = __builtin_amdgcn_mfma_f32_16x16x32_bf16(af[mi], bfr[ni], acc[mi][ni], 0, 0, 0);
            asm volatile("" ::: "memory");
            __builtin_amdgcn_s_barrier();
            asm volatile("" ::: "memory");
            if (t + 2 < NT) {
                int k = (t + 2) * 32;
                gload16(a0 + k, ldsA0 + o);
                gload16(a1 + k, ldsA1 + o);
                gload16(b0 + k, ldsB0 + o);
                gload16(b1 + k, ldsB1 + o);
            }
            cur ^= 1;
        }

        // epilogue: fused combine of this K-half's partial
#pragma unroll
        for (int mi = 0; mi < 4; mi++) {
#pragma unroll
            for (int i = 0; i < 4; i++) {
                int rr = m0 + wm * 64 + mi * 16 + quad * 4 + i;
                if (rr < cnt) {
                    int pos = bs + rr;
                    int tok = list_tok[pos];
                    float p = list_prob[pos];
                    float* yp = out + (size_t)tok * Dd + n0 + wn * 64;
#pragma unroll
                    for (int ni = 0; ni < 4; ni++)
                        atomicAdd(&yp[ni * 16 + lane15], p * acc[mi][ni][i]);
                }
            }
        }
    }
}

// ============ fallback routed GEMM (fp32 weights, correctness-first) ============
template <int EPI>
__global__ __launch_bounds__(256) void rgemm_kernel(
    const unsigned short* __restrict__ A,
    const float* __restrict__ Bw,
    unsigned short* __restrict__ h1raw,
    unsigned short* __restrict__ hout,
    float* __restrict__ out,
    const int* __restrict__ list_tok, const float* __restrict__ list_prob,
    const int* __restrict__ meta,
    int AK, int BN, int arow_is_list) {
    int e = blockIdx.z;
    int cnt = meta[e];
    int m0 = blockIdx.y * 128;
    if (m0 >= cnt) return;
    int bs = meta[16 + e];
    int n0 = blockIdx.x * 128;

    __shared__ unsigned short sA[2 * 128 * 32];
    __shared__ unsigned short sB[2 * 128 * 32];

    int tid = threadIdx.x;
    int lane = tid & 63, w = tid >> 6;
    int wm = w >> 1, wn = w & 1;
    int lane15 = lane & 15, quad = lane >> 4;

    int jr = w * 32 + (lane >> 2);
    int c8 = (lane & 3) * 8;
    unsigned short* ldsA0 = sA + w * 1024;
    unsigned short* ldsA1 = ldsA0 + 512;

    int r0 = m0 + jr;      if (r0 >= cnt) r0 = cnt - 1;
    int r1 = m0 + jr + 16; if (r1 >= cnt) r1 = cnt - 1;
    size_t ar0 = arow_is_list ? (size_t)list_tok[bs + r0] : (size_t)(bs + r0);
    size_t ar1 = arow_is_list ? (size_t)list_tok[bs + r1] : (size_t)(bs + r1);
    const unsigned short* a0 = A + ar0 * AK + c8;
    const unsigned short* a1 = A + ar1 * AK + c8;

    int row = tid >> 1, colb = (tid & 1) * 16;
    const float* bmp = Bw + ((size_t)e * BN + n0 + row) * AK + colb;
    unsigned short* sBw = &sB[row * 32 + colb];

    const unsigned short* sAr = &sA[(wm * 64 + lane15) * 32 + quad * 8];
    const unsigned short* sBr = &sB[(wn * 64 + lane15) * 32 + quad * 8];

    floatx4 acc[4][4] = {};

    gload16(a0, ldsA0);
    gload16(a1, ldsA1);
    stage16(sBw, bmp);
    __syncthreads();
    int cur = 0;
    for (int k0 = 0; k0 < AK; k0 += 32) {
        if (k0 + 32 < AK) {
            int o = (cur ^ 1) * 4096;
            int k = k0 + 32;
            gload16(a0 + k, ldsA0 + o);
            gload16(a1 + k, ldsA1 + o);
            stage16(sBw + o, bmp + k);
        }
        int o = cur * 4096;
        short8 af[4], bfr[4];
#pragma unroll
        for (int i = 0; i < 4; i++) {
            af[i]  = *reinterpret_cast<const short8*>(sAr + o + i * 16 * 32);
            bfr[i] = *reinterpret_cast<const short8*>(sBr + o + i * 16 * 32);
        }
#pragma unroll
        for (int mi = 0; mi < 4; mi++)
#pragma unroll
            for (int ni = 0; ni < 4; ni++)
                acc[mi][ni] = __builtin_amdgcn_mfma_f32_16x16x32_bf16(af[mi], bfr[ni], acc[mi][ni], 0, 0, 0);
        __syncthreads();
        cur ^= 1;
    }

#pragma unroll
    for (int mi = 0; mi < 4; mi++) {
#pragma unroll
        for (int i = 0; i < 4; i++) {
            int rr = m0 + wm * 64 + mi * 16 + quad * 4 + i;
            if (rr < cnt) {
                int pos = bs + rr;
                if constexpr (EPI == 0) {
                    unsigned short* hp = h1raw + (size_t)pos * BN + n0 + wn * 64;
#pragma unroll
                    for (int ni = 0; ni < 4; ni++)
                        hp[ni * 16 + lane15] = f2bf(acc[mi][ni][i]);
                } else if constexpr (EPI == 1) {
                    const unsigned short* h1p = h1raw + (size_t)pos * BN + n0 + wn * 64;
                    unsigned short* hp = hout + (size_t)pos * BN + n0 + wn * 64;
#pragma unroll
                    for (int ni = 0; ni < 4; ni++) {
                        float h1 = bf2f(h1p[ni * 16 + lane15]);
                        float h2 = acc[mi][ni][i];
                        float hv = h1 / (1.f + expf(-h1)) * h2;
                        hp[ni * 16 + lane15] = f2bf(hv);
                    }
                } else {
                    int tok = list_tok[pos];
                    float p = list_prob[pos];
                    float* yp = out + (size_t)tok * BN + n0 + wn * 64;
#pragma unroll
                    for (int ni = 0; ni < 4; ni++)
                        atomicAdd(&yp[ni * 16 + lane15], p * acc[mi][ni][i]);
                }
            }
        }
    }
}

// ---------------- host launch ----------------
extern "C" void kernel_launch(void* const* d_in, const int* in_sizes, int n_in,
                              void* d_out, int out_size, void* d_ws, size_t ws_size,
                              hipStream_t stream) {
    const float* x  = (const float*)d_in[0];
    const float* Wg = (const float*)d_in[1];
    const float* W1 = (const float*)d_in[2];
    const float* W2 = (const float*)d_in[3];
    const float* W3 = (const float*)d_in[4];
    float* out = (float*)d_out;

    char* ws = (char*)d_ws;
    size_t off = 0;
    auto alloc = [&](size_t bytes) -> char* {
        size_t o = off;
        off += (bytes + 255) & ~(size_t)255;
        return ws + o;
    };

    int* meta = (int*)alloc(64 * sizeof(int));
    int* ctr = (int*)alloc(32 * sizeof(int));       // ctr[8] + ctr2[8]
    int* ctr2 = ctr + 16;
    int* tok_idx = (int*)alloc((size_t)TOK * 2 * sizeof(int));
    float* tok_prob = (float*)alloc((size_t)TOK * 2 * sizeof(float));
    int* list_tok = (int*)alloc((size_t)PAIRS * sizeof(int));
    float* list_prob = (float*)alloc((size_t)PAIRS * sizeof(float));
    unsigned short* xb = (unsigned short*)alloc((size_t)TOK * Dd * sizeof(unsigned short));
    unsigned short* hidden = (unsigned short*)alloc((size_t)PAIRS * Ff * sizeof(unsigned short));
    unsigned short* h1raw = (unsigned short*)alloc((size_t)PAIRS * Ff * sizeof(unsigned short));  // fallback path only

    // bf16 weight copies
    size_t wbytes = (size_t)Ee * Ff * Dd * sizeof(unsigned short);
    bool has_w = (ws_size >= off + 3 * wbytes + 4096);
    unsigned short *W1b = nullptr, *W2b = nullptr, *W3b = nullptr;
    if (has_w) {
        W1b = (unsigned short*)alloc(wbytes);
        W2b = (unsigned short*)alloc(wbytes);
        W3b = (unsigned short*)alloc(wbytes);
    }

    // out pre-zeroed for the atomic-accumulate epilogue; ctr zeroed for routing
    zero_kernel<<<dim3(TOK * Dd / 4 / 256), dim3(256), 0, stream>>>(out, TOK * Dd / 4);
    hipMemsetAsync(ctr, 0, 32 * sizeof(int), stream);

    gating_kernel<<<dim3(TOK / 4), dim3(256), 0, stream>>>(x, Wg, tok_idx, tok_prob, xb);
    route_count<<<dim3(PAIRS / 256), dim3(256), 0, stream>>>(tok_idx, ctr);
    route_scan<<<dim3(1), dim3(64), 0, stream>>>(ctr, meta, ctr2);
    route_scatter<<<dim3(PAIRS / 256), dim3(256), 0, stream>>>(tok_idx, tok_prob, meta,
                                                               ctr2, list_tok, list_prob);

    if (has_w) {
        dim3 blk(256);
        // all three weights in one grid-stride launch
        wcvt_kernel<<<dim3(8192), blk, 0, stream>>>(W1, W2, W3, W1b, W2b, W3b);
        // fused gemm1: persistent 768 blocks (3/CU), active tiles only
        rgemm12_kernel<<<dim3(768), blk, 0, stream>>>(
            xb, W1b, W2b, hidden, list_tok, meta);
        // gemm2 + combine: persistent 1024 blocks (4/CU), split-K2
        rg2_kernel<<<dim3(1024), blk, 0, stream>>>(
            hidden, W3b, out, list_tok, list_prob, meta);
    } else {
        dim3 g1(Ff / 128, 32, Ee), g2(Dd / 128, 32, Ee), blk(256);
        rgemm_kernel<0><<<g1, blk, 0, stream>>>(
            xb, W1, h1raw, nullptr, nullptr, list_tok, list_prob, meta, Dd, Ff, 1);
        rgemm_kernel<1><<<g1, blk, 0, stream>>>(
            xb, W2, h1raw, hidden, nullptr, list_tok, list_prob, meta, Dd, Ff, 1);
        rgemm_kernel<2><<<g2, blk, 0, stream>>>(
            hidden, W3, nullptr, nullptr, out, list_tok, list_prob, meta, Ff, Dd, 0);
    }
}

// Round 10
// 442.949 us; speedup vs baseline: 1.0290x; 1.0290x over previous
//
#include <hip/hip_runtime.h>
#include <hip/hip_bf16.h>
#include <cstdint>

// MoE feed-forward, routed top-2 of 8 experts.
// B=2 S=2048 D=1024 F=2048 E=8 K=2.
// R15: revert to family-A base (R8 exact, best total 425.5; grid-launched
//   GEMMs). Seven rounds split into two clusters: grid-family {425-428} vs
//   persistent-family {440-456} -- persistent kernels measure faster alone
//   (109 vs 119) but totals are consistently worse (R11 isolated it). Trust
//   totals. ONE change vs R8: split-K2 on gemm2, GRID-launched:
//   grid (8, 64, 8), y = mblk*2+khalf, K=1024 per block -> 1024 active
//   blocks (4/CU) vs 512 (2/CU); partials feed the pre-zeroed atomic
//   combine (4 deterministic-independent adds/elem).
//   (kept from R8: dual-acc fused gemm1 grid 16x32x8 w/ early exit, counted
//    vmcnt 2-deep, XOR chunk swizzle -> 0 bank conflicts, NO setprio,
//    1-block route, separate cvt launches, atomic combine.)
//   Known ceiling: rgemm12 at 27% MfmaUtil is LDS-issue-bound (48KB
//   reads/K-step @ ~85B/cy = 578cy vs 154cy MFMA) -- structural to the
//   2-phase 128^2 shape; next lever would be the 8-phase 256^2 port.

#define Dd 1024
#define Ff 2048
#define Ee 8
#define TOK 4096
#define PAIRS 8192

typedef __attribute__((ext_vector_type(8))) short short8;
typedef __attribute__((ext_vector_type(4))) float floatx4;

__device__ __forceinline__ unsigned short f2bf(float f) {
    unsigned int u = __float_as_uint(f);
    unsigned int r = (u + 0x7FFFu + ((u >> 16) & 1u)) >> 16;
    return (unsigned short)r;
}
__device__ __forceinline__ float bf2f(unsigned short u) {
    return __uint_as_float(((unsigned)u) << 16);
}

// async 16B/lane global->LDS. lds ptr is wave-uniform; lane i lands at lds + i*16B.
__device__ __forceinline__ void gload16(const unsigned short* g, unsigned short* l) {
    __builtin_amdgcn_global_load_lds(
        (const __attribute__((address_space(1))) unsigned int*)g,
        (__attribute__((address_space(3))) unsigned int*)l,
        16, 0, 0);
}

// ---------------- zero out ----------------
__global__ void zero_kernel(float* __restrict__ out, int n4) {
    int i = blockIdx.x * blockDim.x + threadIdx.x;
    if (i < n4) reinterpret_cast<float4*>(out)[i] = make_float4(0.f, 0.f, 0.f, 0.f);
}

// ---------------- gating: fp32 scores, top-2, softmax (NO atomics) ----------------
__global__ void gating_kernel(const float* __restrict__ x, const float* __restrict__ Wg,
                              int* __restrict__ tok_idx, float* __restrict__ tok_prob) {
    int lane = threadIdx.x & 63;
    int w = threadIdx.x >> 6;
    int t = blockIdx.x * 4 + w;

    float xr[16];
    const float* xp = x + (size_t)t * Dd;
#pragma unroll
    for (int i = 0; i < 16; i++) xr[i] = xp[lane + i * 64];

    float sc[Ee];
    for (int e = 0; e < Ee; e++) {
        const float* wp = Wg + (size_t)e * Dd;
        float p = 0.f;
#pragma unroll
        for (int i = 0; i < 16; i++) p += xr[i] * wp[lane + i * 64];
        for (int off = 32; off > 0; off >>= 1) p += __shfl_xor(p, off);
        sc[e] = p;
    }
    if (lane == 0) {
        int e1 = 0, e2 = 0;
        float b1 = -1e30f, b2 = -1e30f;
        for (int e = 0; e < Ee; e++) {
            float s = sc[e];
            if (s > b1) { b2 = b1; e2 = e1; b1 = s; e1 = e; }
            else if (s > b2) { b2 = s; e2 = e; }
        }
        float p1 = 1.f / (1.f + expf(b2 - b1));
        float p2 = 1.f - p1;
        tok_idx[t * 2 + 0] = e1;
        tok_idx[t * 2 + 1] = e2;
        tok_prob[t * 2 + 0] = p1;
        tok_prob[t * 2 + 1] = p2;
    }
}

// ---------------- route: fused count + scan + stable scatter, one block ----------------
__global__ __launch_bounds__(1024) void route_kernel(
    const int* __restrict__ tok_idx, const float* __restrict__ tok_prob,
    int* __restrict__ meta, int* __restrict__ list_tok,
    float* __restrict__ list_prob) {
    int tid = threadIdx.x;
    int lane = tid & 63, w = tid >> 6;   // 16 waves

    int e_loc[8];
#pragma unroll
    for (int j = 0; j < 8; j++) e_loc[j] = tok_idx[tid * 8 + j];

    int h[Ee];
#pragma unroll
    for (int e = 0; e < Ee; e++) {
        int c = 0;
#pragma unroll
        for (int j = 0; j < 8; j++) c += (e_loc[j] == e) ? 1 : 0;
        h[e] = c;
    }

    int pre[Ee], tot[Ee];
#pragma unroll
    for (int e = 0; e < Ee; e++) {
        int v = h[e];
        for (int d = 1; d < 64; d <<= 1) {
            int u = __shfl_up(v, d, 64);
            if (lane >= d) v += u;
        }
        pre[e] = v - h[e];
        tot[e] = __shfl(v, 63, 64);
    }

    __shared__ int wtot[16][Ee];
    __shared__ int wbase[16][Ee];
    __shared__ int ebase[Ee];
    if (lane == 0)
#pragma unroll
        for (int e = 0; e < Ee; e++) wtot[w][e] = tot[e];
    __syncthreads();
    if (tid == 0) {
        int etot[Ee];
        for (int e = 0; e < Ee; e++) {
            int s = 0;
            for (int ww = 0; ww < 16; ww++) { wbase[ww][e] = s; s += wtot[ww][e]; }
            etot[e] = s;
        }
        int b = 0;
        for (int e = 0; e < Ee; e++) {
            ebase[e] = b;
            meta[e] = etot[e];       // counts
            meta[16 + e] = b;        // bases
            b += etot[e];
        }
    }
    __syncthreads();

    int off[Ee];
#pragma unroll
    for (int e = 0; e < Ee; e++) off[e] = ebase[e] + wbase[w][e] + pre[e];

#pragma unroll
    for (int j = 0; j < 8; j++) {
        int item = tid * 8 + j;
        int el = e_loc[j];
        int pos = 0;
#pragma unroll
        for (int e = 0; e < Ee; e++) {
            if (el == e) { pos = off[e]; off[e] = pos + 1; }
        }
        list_tok[pos] = item >> 1;
        list_prob[pos] = tok_prob[item];
    }
}

// ---------------- fp32 -> bf16 convert ----------------
__global__ void cvt_kernel(const float* __restrict__ src, unsigned short* __restrict__ dst, int n4) {
    int i = blockIdx.x * blockDim.x + threadIdx.x;
    if (i >= n4) return;
    float4 v = reinterpret_cast<const float4*>(src)[i];
    uint2 o;
    o.x = (unsigned)f2bf(v.x) | ((unsigned)f2bf(v.y) << 16);
    o.y = (unsigned)f2bf(v.z) | ((unsigned)f2bf(v.w) << 16);
    reinterpret_cast<uint2*>(dst)[i] = o;
}

// ---------------- manual fp32->bf16 LDS staging (fallback path only, linear) ----------------
__device__ __forceinline__ void stage16(unsigned short* dst, const float* src) {
    const float4* s = reinterpret_cast<const float4*>(src);
    float4 v0 = s[0], v1 = s[1], v2 = s[2], v3 = s[3];
    uint4 o0, o1;
    o0.x = (unsigned)f2bf(v0.x) | ((unsigned)f2bf(v0.y) << 16);
    o0.y = (unsigned)f2bf(v0.z) | ((unsigned)f2bf(v0.w) << 16);
    o0.z = (unsigned)f2bf(v1.x) | ((unsigned)f2bf(v1.y) << 16);
    o0.w = (unsigned)f2bf(v1.z) | ((unsigned)f2bf(v1.w) << 16);
    o1.x = (unsigned)f2bf(v2.x) | ((unsigned)f2bf(v2.y) << 16);
    o1.y = (unsigned)f2bf(v2.z) | ((unsigned)f2bf(v2.w) << 16);
    o1.z = (unsigned)f2bf(v3.x) | ((unsigned)f2bf(v3.y) << 16);
    o1.w = (unsigned)f2bf(v3.z) | ((unsigned)f2bf(v3.w) << 16);
    uint4* d = reinterpret_cast<uint4*>(dst);
    d[0] = o0;
    d[1] = o1;
}

// ============ fused gemm1: hidden = silu(x W1^T) * (x W2^T), routed rows ============
// R8 exact: 128x128 tile, BK=32, 4 waves (2Mx2N, 64x64/wave), dual acc,
// counted-vmcnt 2-deep (vmcnt(6)), XOR chunk swizzle, grid w/ early exit.
__global__ __launch_bounds__(256, 2) void rgemm12_kernel(
    const unsigned short* __restrict__ A,      // xb
    const unsigned short* __restrict__ B1w,    // W1b
    const unsigned short* __restrict__ B2w,    // W2b
    unsigned short* __restrict__ hout,         // hidden (bf16)
    const int* __restrict__ list_tok, const int* __restrict__ meta) {
    int e = blockIdx.z;
    int cnt = meta[e];
    int m0 = blockIdx.y * 128;
    if (m0 >= cnt) return;
    int bs = meta[16 + e];
    int n0 = blockIdx.x * 128;

    __shared__ unsigned short sA[2 * 128 * 32];
    __shared__ unsigned short sB1[2 * 128 * 32];
    __shared__ unsigned short sB2[2 * 128 * 32];

    int tid = threadIdx.x;
    int lane = tid & 63, w = tid >> 6;
    int wm = w >> 1, wn = w & 1;
    int lane15 = lane & 15, quad = lane >> 4;

    int jr = w * 32 + (lane >> 2);
    int c8 = (((lane & 3) ^ ((lane >> 3) & 3)) * 8);
    unsigned short* ldsA0  = sA  + w * 1024;
    unsigned short* ldsA1  = ldsA0 + 512;
    unsigned short* ldsB10 = sB1 + w * 1024;
    unsigned short* ldsB11 = ldsB10 + 512;
    unsigned short* ldsB20 = sB2 + w * 1024;
    unsigned short* ldsB21 = ldsB20 + 512;

    int r0 = m0 + jr;      if (r0 >= cnt) r0 = cnt - 1;
    int r1 = m0 + jr + 16; if (r1 >= cnt) r1 = cnt - 1;
    size_t ar0 = (size_t)list_tok[bs + r0];
    size_t ar1 = (size_t)list_tok[bs + r1];
    const unsigned short* a0 = A + ar0 * Dd + c8;
    const unsigned short* a1 = A + ar1 * Dd + c8;
    const unsigned short* b10 = B1w + ((size_t)e * Ff + n0 + jr) * Dd + c8;
    const unsigned short* b11 = b10 + (size_t)16 * Dd;
    const unsigned short* b20 = B2w + ((size_t)e * Ff + n0 + jr) * Dd + c8;
    const unsigned short* b21 = b20 + (size_t)16 * Dd;

    int rsw = (lane15 >> 1) & 3;
    const unsigned short* sAr  = &sA [(wm * 64 + lane15) * 32 + (quad ^ rsw) * 8];
    const unsigned short* sB1r = &sB1[(wn * 64 + lane15) * 32 + (quad ^ rsw) * 8];
    const unsigned short* sB2r = &sB2[(wn * 64 + lane15) * 32 + (quad ^ rsw) * 8];

    floatx4 acc1[4][4] = {};
    floatx4 acc2[4][4] = {};

    // prologue: stage tiles 0 and 1 (12 loads in flight)
#pragma unroll
    for (int t = 0; t < 2; t++) {
        int k = t * 32, o = t * 4096;
        gload16(a0 + k,  ldsA0  + o);
        gload16(a1 + k,  ldsA1  + o);
        gload16(b10 + k, ldsB10 + o);
        gload16(b11 + k, ldsB11 + o);
        gload16(b20 + k, ldsB20 + o);
        gload16(b21 + k, ldsB21 + o);
    }

    int cur = 0;
    for (int t = 0; t < 32; ++t) {
        if (t < 31) asm volatile("s_waitcnt vmcnt(6)" ::: "memory");
        else        asm volatile("s_waitcnt vmcnt(0)" ::: "memory");
        __builtin_amdgcn_s_barrier();
        asm volatile("" ::: "memory");

        int o = cur * 4096;
        short8 af[4], b1f[4], b2f[4];
#pragma unroll
        for (int i = 0; i < 4; i++) {
            af[i]  = *reinterpret_cast<const short8*>(sAr  + o + i * 16 * 32);
            b1f[i] = *reinterpret_cast<const short8*>(sB1r + o + i * 16 * 32);
            b2f[i] = *reinterpret_cast<const short8*>(sB2r + o + i * 16 * 32);
        }
#pragma unroll
        for (int mi = 0; mi < 4; mi++)
#pragma unroll
            for (int ni = 0; ni < 4; ni++) {
                acc1[mi][ni] = __builtin_amdgcn_mfma_f32_16x16x32_bf16(af[mi], b1f[ni], acc1[mi][ni], 0, 0, 0);
                acc2[mi][ni] = __builtin_amdgcn_mfma_f32_16x16x32_bf16(af[mi], b2f[ni], acc2[mi][ni], 0, 0, 0);
            }
        asm volatile("" ::: "memory");
        __builtin_amdgcn_s_barrier();   // all waves done reading buf[cur]
        asm volatile("" ::: "memory");
        if (t + 2 < 32) {               // restage buf[cur] with tile t+2
            int k = (t + 2) * 32;
            gload16(a0 + k,  ldsA0  + o);
            gload16(a1 + k,  ldsA1  + o);
            gload16(b10 + k, ldsB10 + o);
            gload16(b11 + k, ldsB11 + o);
            gload16(b20 + k, ldsB20 + o);
            gload16(b21 + k, ldsB21 + o);
        }
        cur ^= 1;
    }

    // epilogue: hidden = silu(h1) * h2, silu on full-precision acc
#pragma unroll
    for (int mi = 0; mi < 4; mi++) {
#pragma unroll
        for (int i = 0; i < 4; i++) {
            int rr = m0 + wm * 64 + mi * 16 + quad * 4 + i;
            if (rr < cnt) {
                int pos = bs + rr;
                unsigned short* hp = hout + (size_t)pos * Ff + n0 + wn * 64;
#pragma unroll
                for (int ni = 0; ni < 4; ni++) {
                    float h1 = acc1[mi][ni][i];
                    float h2 = acc2[mi][ni][i];
                    float hv = h1 / (1.f + expf(-h1)) * h2;
                    hp[ni * 16 + lane15] = f2bf(hv);
                }
            }
        }
    }
}

// ============ gemm2 + combine (grid, split-K2): out[tok] += p * (hidden W3^T) ============
// R8 inner loop, K=2048 split into 2 halves of 1024. grid (8, 64, 8):
// y = mblk*2 + khalf -> 1024 active blocks (4/CU). Partials feed the
// pre-zeroed atomic combine (4 deterministic-independent adds/elem).
__global__ __launch_bounds__(256, 2) void rg2k_kernel(
    const unsigned short* __restrict__ A,      // hidden
    const unsigned short* __restrict__ B3,     // W3b (e, d, f)
    float* __restrict__ out,                   // token-indexed atomic output
    const int* __restrict__ list_tok, const float* __restrict__ list_prob,
    const int* __restrict__ meta) {
    int e = blockIdx.z;
    int cnt = meta[e];
    int mblk = blockIdx.y >> 1;
    int kh = blockIdx.y & 1;
    int m0 = mblk * 128;
    if (m0 >= cnt) return;
    int bs = meta[16 + e];
    int n0 = blockIdx.x * 128;
    int k0 = kh * 1024;                // K-half offset (elements)

    __shared__ unsigned short sA[2 * 128 * 32];
    __shared__ unsigned short sB[2 * 128 * 32];

    int tid = threadIdx.x;
    int lane = tid & 63, w = tid >> 6;
    int wm = w >> 1, wn = w & 1;
    int lane15 = lane & 15, quad = lane >> 4;

    int jr = w * 32 + (lane >> 2);
    int c8 = (((lane & 3) ^ ((lane >> 3) & 3)) * 8);
    unsigned short* ldsA0 = sA + w * 1024;
    unsigned short* ldsA1 = ldsA0 + 512;
    unsigned short* ldsB0 = sB + w * 1024;
    unsigned short* ldsB1 = ldsB0 + 512;

    int r0 = m0 + jr;      if (r0 >= cnt) r0 = cnt - 1;
    int r1 = m0 + jr + 16; if (r1 >= cnt) r1 = cnt - 1;
    const unsigned short* a0 = A + (size_t)(bs + r0) * Ff + k0 + c8;   // rows contiguous
    const unsigned short* a1 = A + (size_t)(bs + r1) * Ff + k0 + c8;
    const unsigned short* b0 = B3 + ((size_t)e * Dd + n0 + jr) * Ff + k0 + c8;
    const unsigned short* b1 = b0 + (size_t)16 * Ff;

    int rsw = (lane15 >> 1) & 3;
    const unsigned short* sAr = &sA[(wm * 64 + lane15) * 32 + (quad ^ rsw) * 8];
    const unsigned short* sBr = &sB[(wn * 64 + lane15) * 32 + (quad ^ rsw) * 8];

    floatx4 acc[4][4] = {};

    // prologue: stage tiles 0 and 1 (8 loads in flight)
#pragma unroll
    for (int t = 0; t < 2; t++) {
        int k = t * 32, o = t * 4096;
        gload16(a0 + k, ldsA0 + o);
        gload16(a1 + k, ldsA1 + o);
        gload16(b0 + k, ldsB0 + o);
        gload16(b1 + k, ldsB1 + o);
    }
    int cur = 0;
    const int NT = 32;   // 1024 / 32
    for (int t = 0; t < NT; ++t) {
        if (t + 1 < NT) asm volatile("s_waitcnt vmcnt(4)" ::: "memory");
        else            asm volatile("s_waitcnt vmcnt(0)" ::: "memory");
        __builtin_amdgcn_s_barrier();
        asm volatile("" ::: "memory");

        int o = cur * 4096;
        short8 af[4], bfr[4];
#pragma unroll
        for (int i = 0; i < 4; i++) {
            af[i]  = *reinterpret_cast<const short8*>(sAr + o + i * 16 * 32);
            bfr[i] = *reinterpret_cast<const short8*>(sBr + o + i * 16 * 32);
        }
#pragma unroll
        for (int mi = 0; mi < 4; mi++)
#pragma unroll
            for (int ni = 0; ni < 4; ni++)
                acc[mi][ni] = __builtin_amdgcn_mfma_f32_16x16x32_bf16(af[mi], bfr[ni], acc[mi][ni], 0, 0, 0);
        asm volatile("" ::: "memory");
        __builtin_amdgcn_s_barrier();
        asm volatile("" ::: "memory");
        if (t + 2 < NT) {
            int k = (t + 2) * 32;
            gload16(a0 + k, ldsA0 + o);
            gload16(a1 + k, ldsA1 + o);
            gload16(b0 + k, ldsB0 + o);
            gload16(b1 + k, ldsB1 + o);
        }
        cur ^= 1;
    }

    // epilogue: fused combine of this K-half's partial
#pragma unroll
    for (int mi = 0; mi < 4; mi++) {
#pragma unroll
        for (int i = 0; i < 4; i++) {
            int rr = m0 + wm * 64 + mi * 16 + quad * 4 + i;
            if (rr < cnt) {
                int pos = bs + rr;
                int tok = list_tok[pos];
                float p = list_prob[pos];
                float* yp = out + (size_t)tok * Dd + n0 + wn * 64;
#pragma unroll
                for (int ni = 0; ni < 4; ni++)
                    atomicAdd(&yp[ni * 16 + lane15], p * acc[mi][ni][i]);
            }
        }
    }
}

// ============ fallback routed GEMM (fp32 weights, correctness-first) ============
template <int EPI>
__global__ __launch_bounds__(256) void rgemm_kernel(
    const unsigned short* __restrict__ A,
    const float* __restrict__ Bw,
    unsigned short* __restrict__ h1raw,
    unsigned short* __restrict__ hout,
    float* __restrict__ out,
    const int* __restrict__ list_tok, const float* __restrict__ list_prob,
    const int* __restrict__ meta,
    int AK, int BN, int arow_is_list) {
    int e = blockIdx.z;
    int cnt = meta[e];
    int m0 = blockIdx.y * 128;
    if (m0 >= cnt) return;
    int bs = meta[16 + e];
    int n0 = blockIdx.x * 128;

    __shared__ unsigned short sA[2 * 128 * 32];
    __shared__ unsigned short sB[2 * 128 * 32];

    int tid = threadIdx.x;
    int lane = tid & 63, w = tid >> 6;
    int wm = w >> 1, wn = w & 1;
    int lane15 = lane & 15, quad = lane >> 4;

    int jr = w * 32 + (lane >> 2);
    int c8 = (lane & 3) * 8;
    unsigned short* ldsA0 = sA + w * 1024;
    unsigned short* ldsA1 = ldsA0 + 512;

    int r0 = m0 + jr;      if (r0 >= cnt) r0 = cnt - 1;
    int r1 = m0 + jr + 16; if (r1 >= cnt) r1 = cnt - 1;
    size_t ar0 = arow_is_list ? (size_t)list_tok[bs + r0] : (size_t)(bs + r0);
    size_t ar1 = arow_is_list ? (size_t)list_tok[bs + r1] : (size_t)(bs + r1);
    const unsigned short* a0 = A + ar0 * AK + c8;
    const unsigned short* a1 = A + ar1 * AK + c8;

    int row = tid >> 1, colb = (tid & 1) * 16;
    const float* bmp = Bw + ((size_t)e * BN + n0 + row) * AK + colb;
    unsigned short* sBw = &sB[row * 32 + colb];

    const unsigned short* sAr = &sA[(wm * 64 + lane15) * 32 + quad * 8];
    const unsigned short* sBr = &sB[(wn * 64 + lane15) * 32 + quad * 8];

    floatx4 acc[4][4] = {};

    gload16(a0, ldsA0);
    gload16(a1, ldsA1);
    stage16(sBw, bmp);
    __syncthreads();
    int cur = 0;
    for (int k0 = 0; k0 < AK; k0 += 32) {
        if (k0 + 32 < AK) {
            int o = (cur ^ 1) * 4096;
            int k = k0 + 32;
            gload16(a0 + k, ldsA0 + o);
            gload16(a1 + k, ldsA1 + o);
            stage16(sBw + o, bmp + k);
        }
        int o = cur * 4096;
        short8 af[4], bfr[4];
#pragma unroll
        for (int i = 0; i < 4; i++) {
            af[i]  = *reinterpret_cast<const short8*>(sAr + o + i * 16 * 32);
            bfr[i] = *reinterpret_cast<const short8*>(sBr + o + i * 16 * 32);
        }
#pragma unroll
        for (int mi = 0; mi < 4; mi++)
#pragma unroll
            for (int ni = 0; ni < 4; ni++)
                acc[mi][ni] = __builtin_amdgcn_mfma_f32_16x16x32_bf16(af[mi], bfr[ni], acc[mi][ni], 0, 0, 0);
        __syncthreads();
        cur ^= 1;
    }

#pragma unroll
    for (int mi = 0; mi < 4; mi++) {
#pragma unroll
        for (int i = 0; i < 4; i++) {
            int rr = m0 + wm * 64 + mi * 16 + quad * 4 + i;
            if (rr < cnt) {
                int pos = bs + rr;
                if constexpr (EPI == 0) {
                    unsigned short* hp = h1raw + (size_t)pos * BN + n0 + wn * 64;
#pragma unroll
                    for (int ni = 0; ni < 4; ni++)
                        hp[ni * 16 + lane15] = f2bf(acc[mi][ni][i]);
                } else if constexpr (EPI == 1) {
                    const unsigned short* h1p = h1raw + (size_t)pos * BN + n0 + wn * 64;
                    unsigned short* hp = hout + (size_t)pos * BN + n0 + wn * 64;
#pragma unroll
                    for (int ni = 0; ni < 4; ni++) {
                        float h1 = bf2f(h1p[ni * 16 + lane15]);
                        float h2 = acc[mi][ni][i];
                        float hv = h1 / (1.f + expf(-h1)) * h2;
                        hp[ni * 16 + lane15] = f2bf(hv);
                    }
                } else {
                    int tok = list_tok[pos];
                    float p = list_prob[pos];
                    float* yp = out + (size_t)tok * BN + n0 + wn * 64;
#pragma unroll
                    for (int ni = 0; ni < 4; ni++)
                        atomicAdd(&yp[ni * 16 + lane15], p * acc[mi][ni][i]);
                }
            }
        }
    }
}

// ---------------- host launch ----------------
extern "C" void kernel_launch(void* const* d_in, const int* in_sizes, int n_in,
                              void* d_out, int out_size, void* d_ws, size_t ws_size,
                              hipStream_t stream) {
    const float* x  = (const float*)d_in[0];
    const float* Wg = (const float*)d_in[1];
    const float* W1 = (const float*)d_in[2];
    const float* W2 = (const float*)d_in[3];
    const float* W3 = (const float*)d_in[4];
    float* out = (float*)d_out;

    char* ws = (char*)d_ws;
    size_t off = 0;
    auto alloc = [&](size_t bytes) -> char* {
        size_t o = off;
        off += (bytes + 255) & ~(size_t)255;
        return ws + o;
    };

    int* meta = (int*)alloc(64 * sizeof(int));
    int* tok_idx = (int*)alloc((size_t)TOK * 2 * sizeof(int));
    float* tok_prob = (float*)alloc((size_t)TOK * 2 * sizeof(float));
    int* list_tok = (int*)alloc((size_t)PAIRS * sizeof(int));
    float* list_prob = (float*)alloc((size_t)PAIRS * sizeof(float));
    unsigned short* xb = (unsigned short*)alloc((size_t)TOK * Dd * sizeof(unsigned short));
    unsigned short* hidden = (unsigned short*)alloc((size_t)PAIRS * Ff * sizeof(unsigned short));
    unsigned short* h1raw = (unsigned short*)alloc((size_t)PAIRS * Ff * sizeof(unsigned short));  // fallback path only

    // bf16 weight copies
    size_t wbytes = (size_t)Ee * Ff * Dd * sizeof(unsigned short);
    bool has_w = (ws_size >= off + 3 * wbytes + 4096);
    unsigned short *W1b = nullptr, *W2b = nullptr, *W3b = nullptr;
    if (has_w) {
        W1b = (unsigned short*)alloc(wbytes);
        W2b = (unsigned short*)alloc(wbytes);
        W3b = (unsigned short*)alloc(wbytes);
    }

    // out pre-zeroed for the atomic-accumulate epilogue
    zero_kernel<<<dim3(TOK * Dd / 4 / 256), dim3(256), 0, stream>>>(out, TOK * Dd / 4);

    gating_kernel<<<dim3(TOK / 4), dim3(256), 0, stream>>>(x, Wg, tok_idx, tok_prob);
    route_kernel<<<dim3(1), dim3(1024), 0, stream>>>(tok_idx, tok_prob, meta,
                                                     list_tok, list_prob);

    int xn4 = TOK * Dd / 4;
    cvt_kernel<<<dim3((xn4 + 255) / 256), dim3(256), 0, stream>>>(x, xb, xn4);

    if (has_w) {
        dim3 blk(256);
        int wn4 = Ee * Ff * Dd / 4;
        cvt_kernel<<<dim3((wn4 + 255) / 256), blk, 0, stream>>>(W1, W1b, wn4);
        cvt_kernel<<<dim3((wn4 + 255) / 256), blk, 0, stream>>>(W2, W2b, wn4);
        cvt_kernel<<<dim3((wn4 + 255) / 256), blk, 0, stream>>>(W3, W3b, wn4);
        // fused gemm1: hidden = silu(x W1^T) * (x W2^T)
        dim3 g1(Ff / 128, 32, Ee);
        rgemm12_kernel<<<g1, blk, 0, stream>>>(
            xb, W1b, W2b, hidden, list_tok, meta);
        // gemm2 + combine, split-K2: grid (8 nblk, 64 = 32 mblk x 2 khalf, 8 e)
        dim3 g2(Dd / 128, 64, Ee);
        rg2k_kernel<<<g2, blk, 0, stream>>>(
            hidden, W3b, out, list_tok, list_prob, meta);
    } else {
        dim3 g1(Ff / 128, 32, Ee), g2(Dd / 128, 32, Ee), blk(256);
        rgemm_kernel<0><<<g1, blk, 0, stream>>>(
            xb, W1, h1raw, nullptr, nullptr, list_tok, list_prob, meta, Dd, Ff, 1);
        rgemm_kernel<1><<<g1, blk, 0, stream>>>(
            xb, W2, h1raw, hidden, nullptr, list_tok, list_prob, meta, Dd, Ff, 1);
        rgemm_kernel<2><<<g2, blk, 0, stream>>>(
            hidden, W3, nullptr, nullptr, out, list_tok, list_prob, meta, Ff, Dd, 0);
    }
}

// Round 11
// 412.754 us; speedup vs baseline: 1.1042x; 1.0732x over previous
//
#include <hip/hip_runtime.h>
#include <hip/hip_bf16.h>
#include <cstdint>

// MoE feed-forward, routed top-2 of 8 experts.
// B=2 S=2048 D=1024 F=2048 E=8 K=2.
// R16: return to R8 exactly (best verified: 425.5 us; every GEMM deviation
//   since -- persistent, setprio, 256x128 tiles, expert pinning, split-K --
//   landed 440-493). GEMM kernels are byte-identical to R8. Only non-GEMM
//   plumbing trimmed (both present in R13, no schedule interaction):
//   (a) x->bf16 fused into gating (row already in regs; -1 launch, -16MB rd)
//   (b) single grid-stride wcvt for all 3 weights (-2 launches).
//   rgemm12 known ceiling: 27% MfmaUtil = LDS-read-issue-bound (578cy
//   ds_read_b128 vs 155cy MFMA per K-step per block) -- structural to the
//   2-phase 128^2 shape.

#define Dd 1024
#define Ff 2048
#define Ee 8
#define TOK 4096
#define PAIRS 8192

typedef __attribute__((ext_vector_type(8))) short short8;
typedef __attribute__((ext_vector_type(4))) float floatx4;

__device__ __forceinline__ unsigned short f2bf(float f) {
    unsigned int u = __float_as_uint(f);
    unsigned int r = (u + 0x7FFFu + ((u >> 16) & 1u)) >> 16;
    return (unsigned short)r;
}
__device__ __forceinline__ float bf2f(unsigned short u) {
    return __uint_as_float(((unsigned)u) << 16);
}

// async 16B/lane global->LDS. lds ptr is wave-uniform; lane i lands at lds + i*16B.
__device__ __forceinline__ void gload16(const unsigned short* g, unsigned short* l) {
    __builtin_amdgcn_global_load_lds(
        (const __attribute__((address_space(1))) unsigned int*)g,
        (__attribute__((address_space(3))) unsigned int*)l,
        16, 0, 0);
}

// ---------------- zero out ----------------
__global__ void zero_kernel(float* __restrict__ out, int n4) {
    int i = blockIdx.x * blockDim.x + threadIdx.x;
    if (i < n4) reinterpret_cast<float4*>(out)[i] = make_float4(0.f, 0.f, 0.f, 0.f);
}

// ---------------- gating + fused x->bf16: fp32 scores, top-2, softmax ----------------
__global__ void gating_kernel(const float* __restrict__ x, const float* __restrict__ Wg,
                              int* __restrict__ tok_idx, float* __restrict__ tok_prob,
                              unsigned short* __restrict__ xb) {
    int lane = threadIdx.x & 63;
    int w = threadIdx.x >> 6;
    int t = blockIdx.x * 4 + w;

    float xr[16];
    const float* xp = x + (size_t)t * Dd;
#pragma unroll
    for (int i = 0; i < 16; i++) xr[i] = xp[lane + i * 64];

    // fused x -> bf16 (row already in registers; replaces the x cvt launch)
    unsigned short* xbp = xb + (size_t)t * Dd;
#pragma unroll
    for (int i = 0; i < 16; i++) xbp[lane + i * 64] = f2bf(xr[i]);

    float sc[Ee];
    for (int e = 0; e < Ee; e++) {
        const float* wp = Wg + (size_t)e * Dd;
        float p = 0.f;
#pragma unroll
        for (int i = 0; i < 16; i++) p += xr[i] * wp[lane + i * 64];
        for (int off = 32; off > 0; off >>= 1) p += __shfl_xor(p, off);
        sc[e] = p;
    }
    if (lane == 0) {
        int e1 = 0, e2 = 0;
        float b1 = -1e30f, b2 = -1e30f;
        for (int e = 0; e < Ee; e++) {
            float s = sc[e];
            if (s > b1) { b2 = b1; e2 = e1; b1 = s; e1 = e; }
            else if (s > b2) { b2 = s; e2 = e; }
        }
        float p1 = 1.f / (1.f + expf(b2 - b1));
        float p2 = 1.f - p1;
        tok_idx[t * 2 + 0] = e1;
        tok_idx[t * 2 + 1] = e2;
        tok_prob[t * 2 + 0] = p1;
        tok_prob[t * 2 + 1] = p2;
    }
}

// ---------------- route: fused count + scan + stable scatter, one block ----------------
__global__ __launch_bounds__(1024) void route_kernel(
    const int* __restrict__ tok_idx, const float* __restrict__ tok_prob,
    int* __restrict__ meta, int* __restrict__ list_tok,
    float* __restrict__ list_prob) {
    int tid = threadIdx.x;
    int lane = tid & 63, w = tid >> 6;   // 16 waves

    int e_loc[8];
#pragma unroll
    for (int j = 0; j < 8; j++) e_loc[j] = tok_idx[tid * 8 + j];

    int h[Ee];
#pragma unroll
    for (int e = 0; e < Ee; e++) {
        int c = 0;
#pragma unroll
        for (int j = 0; j < 8; j++) c += (e_loc[j] == e) ? 1 : 0;
        h[e] = c;
    }

    int pre[Ee], tot[Ee];
#pragma unroll
    for (int e = 0; e < Ee; e++) {
        int v = h[e];
        for (int d = 1; d < 64; d <<= 1) {
            int u = __shfl_up(v, d, 64);
            if (lane >= d) v += u;
        }
        pre[e] = v - h[e];
        tot[e] = __shfl(v, 63, 64);
    }

    __shared__ int wtot[16][Ee];
    __shared__ int wbase[16][Ee];
    __shared__ int ebase[Ee];
    if (lane == 0)
#pragma unroll
        for (int e = 0; e < Ee; e++) wtot[w][e] = tot[e];
    __syncthreads();
    if (tid == 0) {
        int etot[Ee];
        for (int e = 0; e < Ee; e++) {
            int s = 0;
            for (int ww = 0; ww < 16; ww++) { wbase[ww][e] = s; s += wtot[ww][e]; }
            etot[e] = s;
        }
        int b = 0;
        for (int e = 0; e < Ee; e++) {
            ebase[e] = b;
            meta[e] = etot[e];       // counts
            meta[16 + e] = b;        // bases
            b += etot[e];
        }
    }
    __syncthreads();

    int off[Ee];
#pragma unroll
    for (int e = 0; e < Ee; e++) off[e] = ebase[e] + wbase[w][e] + pre[e];

#pragma unroll
    for (int j = 0; j < 8; j++) {
        int item = tid * 8 + j;
        int el = e_loc[j];
        int pos = 0;
#pragma unroll
        for (int e = 0; e < Ee; e++) {
            if (el == e) { pos = off[e]; off[e] = pos + 1; }
        }
        list_tok[pos] = item >> 1;
        list_prob[pos] = tok_prob[item];
    }
}

// ---------------- all-weights fp32 -> bf16, one grid-stride launch ----------------
__global__ void wcvt_kernel(const float* __restrict__ W1, const float* __restrict__ W2,
                            const float* __restrict__ W3,
                            unsigned short* __restrict__ W1b, unsigned short* __restrict__ W2b,
                            unsigned short* __restrict__ W3b) {
    const int n4 = Ee * Ff * Dd / 4;          // 4M = 2^22
    int stride = gridDim.x * blockDim.x;
    for (int i = blockIdx.x * blockDim.x + threadIdx.x; i < 3 * n4; i += stride) {
        int t = i >> 22;
        int j = i & (n4 - 1);
        const float* src = (t == 0) ? W1 : (t == 1) ? W2 : W3;
        unsigned short* dst = (t == 0) ? W1b : (t == 1) ? W2b : W3b;
        float4 v = reinterpret_cast<const float4*>(src)[j];
        uint2 o;
        o.x = (unsigned)f2bf(v.x) | ((unsigned)f2bf(v.y) << 16);
        o.y = (unsigned)f2bf(v.z) | ((unsigned)f2bf(v.w) << 16);
        reinterpret_cast<uint2*>(dst)[j] = o;
    }
}

// ---------------- manual fp32->bf16 LDS staging (fallback path only, linear) ----------------
__device__ __forceinline__ void stage16(unsigned short* dst, const float* src) {
    const float4* s = reinterpret_cast<const float4*>(src);
    float4 v0 = s[0], v1 = s[1], v2 = s[2], v3 = s[3];
    uint4 o0, o1;
    o0.x = (unsigned)f2bf(v0.x) | ((unsigned)f2bf(v0.y) << 16);
    o0.y = (unsigned)f2bf(v0.z) | ((unsigned)f2bf(v0.w) << 16);
    o0.z = (unsigned)f2bf(v1.x) | ((unsigned)f2bf(v1.y) << 16);
    o0.w = (unsigned)f2bf(v1.z) | ((unsigned)f2bf(v1.w) << 16);
    o1.x = (unsigned)f2bf(v2.x) | ((unsigned)f2bf(v2.y) << 16);
    o1.y = (unsigned)f2bf(v2.z) | ((unsigned)f2bf(v2.w) << 16);
    o1.z = (unsigned)f2bf(v3.x) | ((unsigned)f2bf(v3.y) << 16);
    o1.w = (unsigned)f2bf(v3.z) | ((unsigned)f2bf(v3.w) << 16);
    uint4* d = reinterpret_cast<uint4*>(dst);
    d[0] = o0;
    d[1] = o1;
}

// ============ fused gemm1: hidden = silu(x W1^T) * (x W2^T), routed rows ============
// R8 exact: 128x128 tile, BK=32, dual accumulator, counted-vmcnt 2-deep
// (vmcnt(6), never 0 in loop), XOR chunk swizzle both sides, NO setprio.
__global__ __launch_bounds__(256, 2) void rgemm12_kernel(
    const unsigned short* __restrict__ A,      // xb
    const unsigned short* __restrict__ B1w,    // W1b
    const unsigned short* __restrict__ B2w,    // W2b
    unsigned short* __restrict__ hout,         // hidden (bf16)
    const int* __restrict__ list_tok, const int* __restrict__ meta) {
    int e = blockIdx.z;
    int cnt = meta[e];
    int m0 = blockIdx.y * 128;
    if (m0 >= cnt) return;
    int bs = meta[16 + e];
    int n0 = blockIdx.x * 128;

    __shared__ unsigned short sA[2 * 128 * 32];
    __shared__ unsigned short sB1[2 * 128 * 32];
    __shared__ unsigned short sB2[2 * 128 * 32];

    int tid = threadIdx.x;
    int lane = tid & 63, w = tid >> 6;
    int wm = w >> 1, wn = w & 1;
    int lane15 = lane & 15, quad = lane >> 4;

    // staging geometry: wave w stages rows [w*32, w*32+16) then +16.
    // swizzled source chunk: lane's row jr has (jr>>1)&3 == (lane>>3)&3.
    int jr = w * 32 + (lane >> 2);
    int c8 = (((lane & 3) ^ ((lane >> 3) & 3)) * 8);
    unsigned short* ldsA0  = sA  + w * 1024;
    unsigned short* ldsA1  = ldsA0 + 512;
    unsigned short* ldsB10 = sB1 + w * 1024;
    unsigned short* ldsB11 = ldsB10 + 512;
    unsigned short* ldsB20 = sB2 + w * 1024;
    unsigned short* ldsB21 = ldsB20 + 512;

    int r0 = m0 + jr;      if (r0 >= cnt) r0 = cnt - 1;
    int r1 = m0 + jr + 16; if (r1 >= cnt) r1 = cnt - 1;
    size_t ar0 = (size_t)list_tok[bs + r0];
    size_t ar1 = (size_t)list_tok[bs + r1];
    const unsigned short* a0 = A + ar0 * Dd + c8;
    const unsigned short* a1 = A + ar1 * Dd + c8;
    const unsigned short* b10 = B1w + ((size_t)e * Ff + n0 + jr) * Dd + c8;
    const unsigned short* b11 = b10 + (size_t)16 * Dd;
    const unsigned short* b20 = B2w + ((size_t)e * Ff + n0 + jr) * Dd + c8;
    const unsigned short* b21 = b20 + (size_t)16 * Dd;

    // read-side swizzle: fragment row is (..+lane15); (row>>1)&3 == (lane15>>1)&3,
    // independent of mi/wm -> folds into the base pointer.
    int rsw = (lane15 >> 1) & 3;
    const unsigned short* sAr  = &sA [(wm * 64 + lane15) * 32 + (quad ^ rsw) * 8];
    const unsigned short* sB1r = &sB1[(wn * 64 + lane15) * 32 + (quad ^ rsw) * 8];
    const unsigned short* sB2r = &sB2[(wn * 64 + lane15) * 32 + (quad ^ rsw) * 8];

    floatx4 acc1[4][4] = {};
    floatx4 acc2[4][4] = {};

    // prologue: stage tiles 0 and 1 (12 loads in flight)
#pragma unroll
    for (int t = 0; t < 2; t++) {
        int k = t * 32, o = t * 4096;
        gload16(a0 + k,  ldsA0  + o);
        gload16(a1 + k,  ldsA1  + o);
        gload16(b10 + k, ldsB10 + o);
        gload16(b11 + k, ldsB11 + o);
        gload16(b20 + k, ldsB20 + o);
        gload16(b21 + k, ldsB21 + o);
    }

    int cur = 0;
    for (int t = 0; t < 32; ++t) {
        // wait ONLY this tile's 6 loads (next tile's 6 stay in flight)
        if (t < 31) asm volatile("s_waitcnt vmcnt(6)" ::: "memory");
        else        asm volatile("s_waitcnt vmcnt(0)" ::: "memory");
        __builtin_amdgcn_s_barrier();
        asm volatile("" ::: "memory");

        int o = cur * 4096;
        short8 af[4], b1f[4], b2f[4];
#pragma unroll
        for (int i = 0; i < 4; i++) {
            af[i]  = *reinterpret_cast<const short8*>(sAr  + o + i * 16 * 32);
            b1f[i] = *reinterpret_cast<const short8*>(sB1r + o + i * 16 * 32);
            b2f[i] = *reinterpret_cast<const short8*>(sB2r + o + i * 16 * 32);
        }
#pragma unroll
        for (int mi = 0; mi < 4; mi++)
#pragma unroll
            for (int ni = 0; ni < 4; ni++) {
                acc1[mi][ni] = __builtin_amdgcn_mfma_f32_16x16x32_bf16(af[mi], b1f[ni], acc1[mi][ni], 0, 0, 0);
                acc2[mi][ni] = __builtin_amdgcn_mfma_f32_16x16x32_bf16(af[mi], b2f[ni], acc2[mi][ni], 0, 0, 0);
            }
        asm volatile("" ::: "memory");
        __builtin_amdgcn_s_barrier();   // all waves done reading buf[cur]
        asm volatile("" ::: "memory");
        if (t + 2 < 32) {               // restage buf[cur] with tile t+2
            int k = (t + 2) * 32;
            gload16(a0 + k,  ldsA0  + o);
            gload16(a1 + k,  ldsA1  + o);
            gload16(b10 + k, ldsB10 + o);
            gload16(b11 + k, ldsB11 + o);
            gload16(b20 + k, ldsB20 + o);
            gload16(b21 + k, ldsB21 + o);
        }
        cur ^= 1;
    }

    // epilogue: hidden = silu(h1) * h2, silu on full-precision acc
#pragma unroll
    for (int mi = 0; mi < 4; mi++) {
#pragma unroll
        for (int i = 0; i < 4; i++) {
            int rr = m0 + wm * 64 + mi * 16 + quad * 4 + i;
            if (rr < cnt) {
                int pos = bs + rr;
                unsigned short* hp = hout + (size_t)pos * Ff + n0 + wn * 64;
#pragma unroll
                for (int ni = 0; ni < 4; ni++) {
                    float h1 = acc1[mi][ni][i];
                    float h2 = acc2[mi][ni][i];
                    float hv = h1 / (1.f + expf(-h1)) * h2;
                    hp[ni * 16 + lane15] = f2bf(hv);
                }
            }
        }
    }
}

// ============ routed single-acc GEMM (R8 exact) ============
// EPI: 0 = store bf16 C to h1raw
//      1 = read h1raw, hidden = silu(h1)*C (bf16)
//      2 = fused combine: atomicAdd(out[tok], prob * C)  (out pre-zeroed)
// bf16 path: counted-vmcnt 2-deep pipeline (vmcnt(4)); fp32 fallback: __syncthreads.
template <typename WT, int EPI>
__global__ __launch_bounds__(256) void rgemm_kernel(
    const unsigned short* __restrict__ A,      // row source (xb or hidden), stride AK
    const WT* __restrict__ Bw,                 // weights, rows of length AK
    unsigned short* __restrict__ h1raw,        // EPI 0 write / EPI 1 read
    unsigned short* __restrict__ hout,         // EPI 1 write
    float* __restrict__ out,                   // EPI 2: token-indexed atomic output
    const int* __restrict__ list_tok, const float* __restrict__ list_prob,
    const int* __restrict__ meta,
    int AK, int BN, int arow_is_list) {
    constexpr bool BF = (sizeof(WT) == 2);
    int e = blockIdx.z;
    int cnt = meta[e];
    int m0 = blockIdx.y * 128;
    if (m0 >= cnt) return;
    int bs = meta[16 + e];
    int n0 = blockIdx.x * 128;

    __shared__ unsigned short sA[2 * 128 * 32];
    __shared__ unsigned short sB[2 * 128 * 32];

    int tid = threadIdx.x;
    int lane = tid & 63, w = tid >> 6;
    int wm = w >> 1, wn = w & 1;
    int lane15 = lane & 15, quad = lane >> 4;

    int jr = w * 32 + (lane >> 2);
    int c8 = BF ? ((((lane & 3) ^ ((lane >> 3) & 3))) * 8) : ((lane & 3) * 8);
    unsigned short* ldsA0 = sA + w * 1024;
    unsigned short* ldsA1 = ldsA0 + 512;
    unsigned short* ldsB0 = sB + w * 1024;
    unsigned short* ldsB1 = ldsB0 + 512;

    int r0 = m0 + jr;      if (r0 >= cnt) r0 = cnt - 1;
    int r1 = m0 + jr + 16; if (r1 >= cnt) r1 = cnt - 1;
    size_t ar0 = arow_is_list ? (size_t)list_tok[bs + r0] : (size_t)(bs + r0);
    size_t ar1 = arow_is_list ? (size_t)list_tok[bs + r1] : (size_t)(bs + r1);
    const unsigned short* a0 = A + ar0 * AK + c8;
    const unsigned short* a1 = A + ar1 * AK + c8;

    const WT *b0 = nullptr, *b1 = nullptr, *bmp = nullptr;
    unsigned short* sBw = nullptr;
    if constexpr (BF) {
        b0 = Bw + ((size_t)e * BN + n0 + jr) * AK + c8;
        b1 = Bw + ((size_t)e * BN + n0 + jr + 16) * AK + c8;
    } else {
        int row = tid >> 1, colb = (tid & 1) * 16;
        bmp = Bw + ((size_t)e * BN + n0 + row) * AK + colb;
        sBw = &sB[row * 32 + colb];
    }

    int rsw = BF ? ((lane15 >> 1) & 3) : 0;
    const unsigned short* sAr = &sA[(wm * 64 + lane15) * 32 + (quad ^ rsw) * 8];
    const unsigned short* sBr = &sB[(wn * 64 + lane15) * 32 + (quad ^ rsw) * 8];

    floatx4 acc[4][4] = {};

    if constexpr (BF) {
        int NT = AK >> 5;
        // prologue: stage tiles 0 and 1 (8 loads in flight)
#pragma unroll
        for (int t = 0; t < 2; t++) {
            int k = t * 32, o = t * 4096;
            gload16(a0 + k, ldsA0 + o);
            gload16(a1 + k, ldsA1 + o);
            gload16(b0 + k, ldsB0 + o);
            gload16(b1 + k, ldsB1 + o);
        }
        int cur = 0;
        for (int t = 0; t < NT; ++t) {
            if (t + 1 < NT) asm volatile("s_waitcnt vmcnt(4)" ::: "memory");
            else            asm volatile("s_waitcnt vmcnt(0)" ::: "memory");
            __builtin_amdgcn_s_barrier();
            asm volatile("" ::: "memory");

            int o = cur * 4096;
            short8 af[4], bfr[4];
#pragma unroll
            for (int i = 0; i < 4; i++) {
                af[i]  = *reinterpret_cast<const short8*>(sAr + o + i * 16 * 32);
                bfr[i] = *reinterpret_cast<const short8*>(sBr + o + i * 16 * 32);
            }
#pragma unroll
            for (int mi = 0; mi < 4; mi++)
#pragma unroll
                for (int ni = 0; ni < 4; ni++)
                    acc[mi][ni] = __builtin_amdgcn_mfma_f32_16x16x32_bf16(af[mi], bfr[ni], acc[mi][ni], 0, 0, 0);
            asm volatile("" ::: "memory");
            __builtin_amdgcn_s_barrier();
            asm volatile("" ::: "memory");
            if (t + 2 < NT) {
                int k = (t + 2) * 32;
                gload16(a0 + k, ldsA0 + o);
                gload16(a1 + k, ldsA1 + o);
                gload16(b0 + k, ldsB0 + o);
                gload16(b1 + k, ldsB1 + o);
            }
            cur ^= 1;
        }
    } else {
        // fp32 fallback: simple dbuf with __syncthreads (correctness-first path)
        gload16(a0, ldsA0);
        gload16(a1, ldsA1);
        stage16(sBw, (const float*)bmp);
        __syncthreads();
        int cur = 0;
        for (int k0 = 0; k0 < AK; k0 += 32) {
            if (k0 + 32 < AK) {
                int o = (cur ^ 1) * 4096;
                int k = k0 + 32;
                gload16(a0 + k, ldsA0 + o);
                gload16(a1 + k, ldsA1 + o);
                stage16(sBw + o, (const float*)(bmp + k));
            }
            int o = cur * 4096;
            short8 af[4], bfr[4];
#pragma unroll
            for (int i = 0; i < 4; i++) {
                af[i]  = *reinterpret_cast<const short8*>(sAr + o + i * 16 * 32);
                bfr[i] = *reinterpret_cast<const short8*>(sBr + o + i * 16 * 32);
            }
#pragma unroll
            for (int mi = 0; mi < 4; mi++)
#pragma unroll
                for (int ni = 0; ni < 4; ni++)
                    acc[mi][ni] = __builtin_amdgcn_mfma_f32_16x16x32_bf16(af[mi], bfr[ni], acc[mi][ni], 0, 0, 0);
            __syncthreads();
            cur ^= 1;
        }
    }

#pragma unroll
    for (int mi = 0; mi < 4; mi++) {
#pragma unroll
        for (int i = 0; i < 4; i++) {
            int rr = m0 + wm * 64 + mi * 16 + quad * 4 + i;
            if (rr < cnt) {
                int pos = bs + rr;
                if constexpr (EPI == 0) {
                    unsigned short* hp = h1raw + (size_t)pos * BN + n0 + wn * 64;
#pragma unroll
                    for (int ni = 0; ni < 4; ni++)
                        hp[ni * 16 + lane15] = f2bf(acc[mi][ni][i]);
                } else if constexpr (EPI == 1) {
                    const unsigned short* h1p = h1raw + (size_t)pos * BN + n0 + wn * 64;
                    unsigned short* hp = hout + (size_t)pos * BN + n0 + wn * 64;
#pragma unroll
                    for (int ni = 0; ni < 4; ni++) {
                        float h1 = bf2f(h1p[ni * 16 + lane15]);
                        float h2 = acc[mi][ni][i];
                        float hv = h1 / (1.f + expf(-h1)) * h2;
                        hp[ni * 16 + lane15] = f2bf(hv);
                    }
                } else {
                    int tok = list_tok[pos];
                    float p = list_prob[pos];
                    float* yp = out + (size_t)tok * BN + n0 + wn * 64;
#pragma unroll
                    for (int ni = 0; ni < 4; ni++)
                        atomicAdd(&yp[ni * 16 + lane15], p * acc[mi][ni][i]);
                }
            }
        }
    }
}

// ---------------- host launch ----------------
extern "C" void kernel_launch(void* const* d_in, const int* in_sizes, int n_in,
                              void* d_out, int out_size, void* d_ws, size_t ws_size,
                              hipStream_t stream) {
    const float* x  = (const float*)d_in[0];
    const float* Wg = (const float*)d_in[1];
    const float* W1 = (const float*)d_in[2];
    const float* W2 = (const float*)d_in[3];
    const float* W3 = (const float*)d_in[4];
    float* out = (float*)d_out;

    char* ws = (char*)d_ws;
    size_t off = 0;
    auto alloc = [&](size_t bytes) -> char* {
        size_t o = off;
        off += (bytes + 255) & ~(size_t)255;
        return ws + o;
    };

    int* meta = (int*)alloc(64 * sizeof(int));
    int* tok_idx = (int*)alloc((size_t)TOK * 2 * sizeof(int));
    float* tok_prob = (float*)alloc((size_t)TOK * 2 * sizeof(float));
    int* list_tok = (int*)alloc((size_t)PAIRS * sizeof(int));
    float* list_prob = (float*)alloc((size_t)PAIRS * sizeof(float));
    unsigned short* xb = (unsigned short*)alloc((size_t)TOK * Dd * sizeof(unsigned short));
    unsigned short* hidden = (unsigned short*)alloc((size_t)PAIRS * Ff * sizeof(unsigned short));
    unsigned short* h1raw = (unsigned short*)alloc((size_t)PAIRS * Ff * sizeof(unsigned short));  // fallback path only

    // bf16 weight copies
    size_t wbytes = (size_t)Ee * Ff * Dd * sizeof(unsigned short);
    bool has_w = (ws_size >= off + 3 * wbytes + 4096);
    unsigned short *W1b = nullptr, *W2b = nullptr, *W3b = nullptr;
    if (has_w) {
        W1b = (unsigned short*)alloc(wbytes);
        W2b = (unsigned short*)alloc(wbytes);
        W3b = (unsigned short*)alloc(wbytes);
    }

    // out pre-zeroed for the atomic-accumulate epilogue
    zero_kernel<<<dim3(TOK * Dd / 4 / 256), dim3(256), 0, stream>>>(out, TOK * Dd / 4);

    gating_kernel<<<dim3(TOK / 4), dim3(256), 0, stream>>>(x, Wg, tok_idx, tok_prob, xb);
    route_kernel<<<dim3(1), dim3(1024), 0, stream>>>(tok_idx, tok_prob, meta,
                                                     list_tok, list_prob);

    if (has_w) {
        dim3 blk(256);
        // all three weights in one grid-stride launch
        wcvt_kernel<<<dim3(4096), blk, 0, stream>>>(W1, W2, W3, W1b, W2b, W3b);
        // fused gemm1: hidden = silu(x W1^T) * (x W2^T)
        dim3 g1(Ff / 128, 32, Ee);
        rgemm12_kernel<<<g1, blk, 0, stream>>>(
            xb, W1b, W2b, hidden, list_tok, meta);
        // gemm2 + combine: out[tok] += prob * (hidden W3^T)   (R8 exact)
        dim3 g2(Dd / 128, 32, Ee);
        rgemm_kernel<unsigned short, 2><<<g2, blk, 0, stream>>>(
            hidden, W3b, nullptr, nullptr, out, list_tok, list_prob, meta, Ff, Dd, 0);
    } else {
        dim3 g1(Ff / 128, 32, Ee), g2(Dd / 128, 32, Ee), blk(256);
        rgemm_kernel<float, 0><<<g1, blk, 0, stream>>>(
            xb, W1, h1raw, nullptr, nullptr, list_tok, list_prob, meta, Dd, Ff, 1);
        rgemm_kernel<float, 1><<<g1, blk, 0, stream>>>(
            xb, W2, h1raw, hidden, nullptr, list_tok, list_prob, meta, Dd, Ff, 1);
        rgemm_kernel<float, 2><<<g2, blk, 0, stream>>>(
            hidden, W3, nullptr, nullptr, out, list_tok, list_prob, meta, Ff, Dd, 0);
    }
}